// Round 1
// baseline (2570.717 us; speedup 1.0000x reference)
//
#include <hip/hip_runtime.h>

// ---------------------------------------------------------------------------
// ErnieLayout encoder, 12 layers, B=2 S=2048 D=768 H=12 DH=64, bf16 MFMA.
// ---------------------------------------------------------------------------

#define BB 2
#define SS 2048
#define DD 768
#define HH 12
#define NLAYER 12
#define MM 4096  // BB*SS

typedef unsigned short u16;
typedef __attribute__((ext_vector_type(8))) short bf16x8;
typedef __attribute__((ext_vector_type(4))) float f32x4;

__device__ __forceinline__ u16 f2bf(float f) {
  unsigned u = __float_as_uint(f);
  unsigned r = (u + 0x7FFFu + ((u >> 16) & 1u)) >> 16;
  return (u16)r;
}
__device__ __forceinline__ float bf2f(unsigned u) {
  return __uint_as_float(u << 16);
}

__device__ __forceinline__ void g2lds16(const void* g, void* l) {
  __builtin_amdgcn_global_load_lds(
      (const __attribute__((address_space(1))) unsigned int*)g,
      (__attribute__((address_space(3))) unsigned int*)l, 16, 0, 0);
}

// --------------------------------------------------------------------------
// hidden fp32 -> bf16
__global__ __launch_bounds__(256) void k_hb(const float4* __restrict__ x,
                                            uint2* __restrict__ o, int n4) {
  int i = blockIdx.x * 256 + threadIdx.x;
  if (i < n4) {
    float4 v = x[i];
    uint2 r;
    r.x = (unsigned)f2bf(v.x) | ((unsigned)f2bf(v.y) << 16);
    r.y = (unsigned)f2bf(v.z) | ((unsigned)f2bf(v.w) << 16);
    o[i] = r;
  }
}

// --------------------------------------------------------------------------
// relative-position bucketing (mirrors reference fp32 math)
__device__ __forceinline__ int bucket1(int rel) {
  int ret = rel > 0 ? 16 : 0;
  int n = rel < 0 ? -rel : rel;
  if (n < 8) return ret + n;
  int v = 8 + (int)(logf((float)n * 0.125f) * 2.8853900817779268f); // 8/ln(16)
  return ret + (v < 15 ? v : 15);
}
__device__ __forceinline__ int bucket2(int rel) {
  int ret = rel > 0 ? 32 : 0;
  int n = rel < 0 ? -rel : rel;
  if (n < 16) return ret + n;
  int v = 16 + (int)(logf((float)n * 0.0625f) * 5.7707801635558537f); // 16/ln(16)
  return ret + (v < 31 ? v : 31);
}

// Bias precompute: layout [b][h][qt(16)][kt(32)][tid(256)][sub(32)] bf16,
// sub = fm*16 + fn*4 + r  (exact order k_attn consumes). Mask folded in.
__global__ __launch_bounds__(256) void k_bias(
    const int* __restrict__ pos, const int* __restrict__ bbx,
    const unsigned char* __restrict__ msk,
    const float* __restrict__ wp, const float* __restrict__ wx,
    const float* __restrict__ wy, u16* __restrict__ bias) {
  int bid = blockIdx.x;                 // b*512 + qt*32 + kt
  int b = bid >> 9, qt = (bid >> 5) & 15, kt = bid & 31;
  __shared__ float swp[384], swx[768], swy[768];
  __shared__ int pq[128], xq[128], yq[128], pk[64], xk[64], yk[64];
  __shared__ unsigned char mk[64];
  int t = threadIdx.x;
  for (int i = t; i < 384; i += 256) swp[i] = wp[i];
  for (int i = t; i < 768; i += 256) { swx[i] = wx[i]; swy[i] = wy[i]; }
  int q0 = qt * 128, k0 = kt * 64;
  if (t < 128) {
    int gi = b * SS + q0 + t;
    pq[t] = pos[gi]; xq[t] = bbx[gi * 4]; yq[t] = bbx[gi * 4 + 3];
  } else if (t < 192) {
    int j = t - 128, gi = b * SS + k0 + j;
    pk[j] = pos[gi]; xk[j] = bbx[gi * 4]; yk[j] = bbx[gi * 4 + 3];
    mk[j] = msk[b * SS + k0 + j];
  }
  __syncthreads();
  int w = t >> 6, l = t & 63;
  int qb_ = w * 32 + ((l >> 4) << 2);
  int kb_ = l & 15;
  int bpv[32], bxv[32], byv[32];
  unsigned mvb = 0;
#pragma unroll
  for (int fm = 0; fm < 2; fm++)
#pragma unroll
    for (int fn = 0; fn < 4; fn++)
#pragma unroll
      for (int r = 0; r < 4; r++) {
        int i = fm * 16 + fn * 4 + r;
        int ql = qb_ + fm * 16 + r, kl = kb_ + fn * 16;
        bpv[i] = bucket1(pk[kl] - pq[ql]);
        bxv[i] = bucket2(xk[kl] - xq[ql]);
        byv[i] = bucket2(yk[kl] - yq[ql]);
        if (mk[kl]) mvb |= (1u << i);
      }
  for (int h = 0; h < 12; h++) {
    const float* rp = swp + h * 32;
    const float* rx = swx + h * 64;
    const float* ry = swy + h * 64;
    unsigned pk2[16];
#pragma unroll
    for (int j = 0; j < 16; j++) {
      float f0 = rp[bpv[2 * j]] + rx[bxv[2 * j]] + ry[byv[2 * j]];
      float f1 = rp[bpv[2 * j + 1]] + rx[bxv[2 * j + 1]] + ry[byv[2 * j + 1]];
      if (mvb & (1u << (2 * j))) f0 = -3.0e38f;
      if (mvb & (1u << (2 * j + 1))) f1 = -3.0e38f;
      pk2[j] = (unsigned)f2bf(f0) | ((unsigned)f2bf(f1) << 16);
    }
    size_t off = ((((size_t)(b * 12 + h) * 16 + qt) * 32 + kt) * 256 + t) * 32;
    uint4* dst = (uint4*)(bias + off);
    dst[0] = make_uint4(pk2[0], pk2[1], pk2[2], pk2[3]);
    dst[1] = make_uint4(pk2[4], pk2[5], pk2[6], pk2[7]);
    dst[2] = make_uint4(pk2[8], pk2[9], pk2[10], pk2[11]);
    dst[3] = make_uint4(pk2[12], pk2[13], pk2[14], pk2[15]);
  }
}

// --------------------------------------------------------------------------
// per-layer weight convert fp32 -> bf16, transposed to [out][in]
__global__ __launch_bounds__(256) void k_wconv(
    const float* __restrict__ qw, const float* __restrict__ kw,
    const float* __restrict__ vw, const float* __restrict__ ow, int layer,
    u16* __restrict__ wt) {
  int bid = blockIdx.x;
  int g = bid / 576, rr_ = bid % 576, nt = rr_ / 24, kt = rr_ % 24;
  const float* src = g == 0 ? qw : g == 1 ? kw : g == 2 ? vw : ow;
  src += (size_t)layer * DD * DD;
  __shared__ float sm[32][33];
  int t = threadIdx.x, c = t & 31, r0 = t >> 5;
#pragma unroll
  for (int p = 0; p < 4; p++) {
    int rr = r0 + p * 8;
    sm[rr][c] = src[(size_t)(kt * 32 + rr) * DD + nt * 32 + c];
  }
  __syncthreads();
  u16* dst = wt + (size_t)g * DD * DD;
#pragma unroll
  for (int p = 0; p < 4; p++) {
    int rn = r0 + p * 8;
    dst[(size_t)(nt * 32 + rn) * DD + kt * 32 + c] = f2bf(sm[c][rn]);
  }
}

// --------------------------------------------------------------------------
// GEMM core: C[128,128] = A[128,768] x Bt[128,768]^T, bf16 MFMA, BK=64,
// XOR-swizzled LDS, global_load_lds(16B) staging with pre-swizzled source.
__device__ __forceinline__ void gemm_core(const u16* __restrict__ A,
                                          const u16* __restrict__ Bt, u16* As,
                                          u16* Bs, f32x4 acc[4][4], int tid) {
  int w = tid >> 6, l = tid & 63;
  int wm = w >> 1, wn = w & 1;
#pragma unroll
  for (int i = 0; i < 4; i++)
#pragma unroll
    for (int j = 0; j < 4; j++) acc[i][j] = f32x4{0.f, 0.f, 0.f, 0.f};
  for (int kt = 0; kt < 12; kt++) {
    __syncthreads();
    int r0 = w * 32;
#pragma unroll
    for (int j = 0; j < 4; j++) {
      int row = r0 + j * 8 + (l >> 3);
      int sl = (l & 7) ^ (row & 7);
      g2lds16(A + (size_t)row * DD + kt * 64 + sl * 8, As + (r0 + j * 8) * 64);
      g2lds16(Bt + (size_t)row * DD + kt * 64 + sl * 8, Bs + (r0 + j * 8) * 64);
    }
    __syncthreads();
#pragma unroll
    for (int kk = 0; kk < 2; kk++) {
      bf16x8 af[4], bfr[4];
#pragma unroll
      for (int fm = 0; fm < 4; fm++) {
        int row = wm * 64 + fm * 16 + (l & 15);
        int slot = (kk * 4 + (l >> 4)) ^ (row & 7);
        af[fm] = *(const bf16x8*)((const char*)As + row * 128 + slot * 16);
      }
#pragma unroll
      for (int fn = 0; fn < 4; fn++) {
        int row = wn * 64 + fn * 16 + (l & 15);
        int slot = (kk * 4 + (l >> 4)) ^ (row & 7);
        bfr[fn] = *(const bf16x8*)((const char*)Bs + row * 128 + slot * 16);
      }
#pragma unroll
      for (int fm = 0; fm < 4; fm++)
#pragma unroll
        for (int fn = 0; fn < 4; fn++)
          acc[fm][fn] = __builtin_amdgcn_mfma_f32_16x16x32_bf16(
              af[fm], bfr[fn], acc[fm][fn], 0, 0, 0);
    }
  }
}

// fused QKV GEMM (N = 3*768), q scaled by 1/sqrt(64)
__global__ __launch_bounds__(256) void k_gemm_qkv(
    const u16* __restrict__ hb, const u16* __restrict__ wt,
    const float* __restrict__ qbias, const float* __restrict__ kbias,
    const float* __restrict__ vbias, u16* __restrict__ qo, u16* __restrict__ ko,
    u16* __restrict__ vo) {
  __shared__ __align__(16) u16 As[128 * 64];
  __shared__ __align__(16) u16 Bs[128 * 64];
  int bid = blockIdx.x;
  int mblk = bid / 18, nblk = bid % 18;
  int g = nblk / 6, nb = nblk % 6;
  const u16* A = hb + (size_t)mblk * 128 * DD;
  const u16* Bt = wt + (size_t)g * DD * DD + (size_t)nb * 128 * DD;
  f32x4 acc[4][4];
  gemm_core(A, Bt, As, Bs, acc, threadIdx.x);
  const float* bias = g == 0 ? qbias : g == 1 ? kbias : vbias;
  u16* out = g == 0 ? qo : g == 1 ? ko : vo;
  float scale = g == 0 ? 0.125f : 1.0f;
  int w = threadIdx.x >> 6, l = threadIdx.x & 63;
  int wm = w >> 1, wn = w & 1;
#pragma unroll
  for (int fn = 0; fn < 4; fn++) {
    int col = nb * 128 + wn * 64 + fn * 16 + (l & 15);
    float bval = bias[col];
#pragma unroll
    for (int fm = 0; fm < 4; fm++)
#pragma unroll
      for (int r = 0; r < 4; r++) {
        int row = mblk * 128 + wm * 64 + fm * 16 + ((l >> 4) << 2) + r;
        out[(size_t)row * DD + col] = f2bf((acc[fm][fn][r] + bval) * scale);
      }
  }
}

// O-projection GEMM, fp32 output (residual+LN done in k_ln)
__global__ __launch_bounds__(256) void k_gemm_o(const u16* __restrict__ ctx,
                                                const u16* __restrict__ wto,
                                                const float* __restrict__ obias,
                                                float* __restrict__ outp) {
  __shared__ __align__(16) u16 As[128 * 64];
  __shared__ __align__(16) u16 Bs[128 * 64];
  int bid = blockIdx.x;
  int mblk = bid / 6, nblk = bid % 6;
  const u16* A = ctx + (size_t)mblk * 128 * DD;
  const u16* Bt = wto + (size_t)nblk * 128 * DD;
  f32x4 acc[4][4];
  gemm_core(A, Bt, As, Bs, acc, threadIdx.x);
  int w = threadIdx.x >> 6, l = threadIdx.x & 63;
  int wm = w >> 1, wn = w & 1;
#pragma unroll
  for (int fn = 0; fn < 4; fn++) {
    int col = nblk * 128 + wn * 64 + fn * 16 + (l & 15);
    float bval = obias[col];
#pragma unroll
    for (int fm = 0; fm < 4; fm++)
#pragma unroll
      for (int r = 0; r < 4; r++) {
        int row = mblk * 128 + wm * 64 + fm * 16 + ((l >> 4) << 2) + r;
        outp[(size_t)row * DD + col] = acc[fm][fn][r] + bval;
      }
  }
}

// --------------------------------------------------------------------------
// V transpose: [B,S,H,DH] -> [B*H][DH=64][S=2048] so attn can stage linearly
__global__ __launch_bounds__(256) void k_vt(const u16* __restrict__ vo,
                                            u16* __restrict__ vt) {
  int bid = blockIdx.x;
  int bh = bid >> 5, st = bid & 31;
  int b = bh / 12, h = bh % 12;
  int s0 = st * 64;
  __shared__ u16 sm[64][68];
  int t = threadIdx.x, c = t & 63, r0 = t >> 6;
#pragma unroll
  for (int p = 0; p < 16; p++) {
    int r = r0 + p * 4;
    sm[r][c] = vo[(size_t)(b * SS + s0 + r) * DD + h * 64 + c];
  }
  __syncthreads();
#pragma unroll
  for (int p = 0; p < 16; p++) {
    int d = r0 + p * 4;
    vt[(size_t)(bh * 64 + d) * SS + s0 + c] = sm[c][d];
  }
}

// --------------------------------------------------------------------------
// Flash attention: block = (b,h,qtile of 128), 4 waves x 32 q-rows, KT=64.
__global__ __launch_bounds__(256) void k_attn(
    const u16* __restrict__ q, const u16* __restrict__ k,
    const u16* __restrict__ vt, const u16* __restrict__ bias,
    u16* __restrict__ ctx) {
  int bid = blockIdx.x;
  int qt = bid & 15, bh = bid >> 4;
  int b = bh / 12, h = bh % 12;
  __shared__ __align__(16) u16 Qs[128 * 64];
  __shared__ __align__(16) u16 Ks[64 * 64];
  __shared__ __align__(16) u16 Vs[64 * 64];
  __shared__ __align__(16) u16 Ps[4 * 32 * 64];
  int tid = threadIdx.x, w = tid >> 6, l = tid & 63;
  int q0 = qt * 128;
  const u16* qb_ = q + (size_t)(b * SS + q0) * DD + h * 64;
  {
    int r0 = w * 32;
#pragma unroll
    for (int j = 0; j < 4; j++) {
      int row = r0 + j * 8 + (l >> 3);
      int sl = (l & 7) ^ (row & 7);
      g2lds16(qb_ + (size_t)row * DD + sl * 8, Qs + (r0 + j * 8) * 64);
    }
  }
  const u16* kb_ = k + (size_t)(b * SS) * DD + h * 64;
  const u16* vb_ = vt + (size_t)bh * 64 * SS;
  const u16* bb_ = bias + ((size_t)(bh * 16 + qt) * 32 * 256 + tid) * 32;
  f32x4 oa[2][4];
  float ms[2][4], ls[2][4];
#pragma unroll
  for (int i = 0; i < 2; i++)
#pragma unroll
    for (int j = 0; j < 4; j++) oa[i][j] = f32x4{0.f, 0.f, 0.f, 0.f};
#pragma unroll
  for (int i = 0; i < 2; i++)
#pragma unroll
    for (int r = 0; r < 4; r++) { ms[i][r] = -3.0e38f; ls[i][r] = 0.f; }
  u16* Pw = Ps + w * 32 * 64;

  for (int kt = 0; kt < 32; kt++) {
    __syncthreads();
#pragma unroll
    for (int j = 0; j < 2; j++) {
      int row = w * 16 + j * 8 + (l >> 3);
      int sl = (l & 7) ^ (row & 7);
      g2lds16(kb_ + (size_t)(kt * 64 + row) * DD + sl * 8,
              Ks + (w * 16 + j * 8) * 64);
      g2lds16(vb_ + (size_t)row * SS + kt * 64 + sl * 8,
              Vs + (w * 16 + j * 8) * 64);
    }
    __syncthreads();
    const uint4* bp = (const uint4*)(bb_ + (size_t)kt * 256 * 32);
    uint4 bv0 = bp[0], bv1 = bp[1], bv2 = bp[2], bv3 = bp[3];
    // QK^T
    f32x4 sc[2][4];
#pragma unroll
    for (int i = 0; i < 2; i++)
#pragma unroll
      for (int j = 0; j < 4; j++) sc[i][j] = f32x4{0.f, 0.f, 0.f, 0.f};
#pragma unroll
    for (int kk = 0; kk < 2; kk++) {
      bf16x8 aq[2], bk[4];
#pragma unroll
      for (int fm = 0; fm < 2; fm++) {
        int row = w * 32 + fm * 16 + (l & 15);
        int slot = (kk * 4 + (l >> 4)) ^ (row & 7);
        aq[fm] = *(const bf16x8*)((const char*)Qs + row * 128 + slot * 16);
      }
#pragma unroll
      for (int fn = 0; fn < 4; fn++) {
        int row = fn * 16 + (l & 15);
        int slot = (kk * 4 + (l >> 4)) ^ (row & 7);
        bk[fn] = *(const bf16x8*)((const char*)Ks + row * 128 + slot * 16);
      }
#pragma unroll
      for (int fm = 0; fm < 2; fm++)
#pragma unroll
        for (int fn = 0; fn < 4; fn++)
          sc[fm][fn] = __builtin_amdgcn_mfma_f32_16x16x32_bf16(
              aq[fm], bk[fn], sc[fm][fn], 0, 0, 0);
    }
    // bias add (pre-blocked layout: sub = fm*16 + fn*4 + r)
    unsigned ua[16] = {bv0.x, bv0.y, bv0.z, bv0.w, bv1.x, bv1.y, bv1.z, bv1.w,
                       bv2.x, bv2.y, bv2.z, bv2.w, bv3.x, bv3.y, bv3.z, bv3.w};
    float bfv[32];
#pragma unroll
    for (int j = 0; j < 16; j++) {
      bfv[2 * j] = bf2f(ua[j] & 0xffffu);
      bfv[2 * j + 1] = bf2f(ua[j] >> 16);
    }
#pragma unroll
    for (int fm = 0; fm < 2; fm++)
#pragma unroll
      for (int fn = 0; fn < 4; fn++)
#pragma unroll
        for (int r = 0; r < 4; r++)
          sc[fm][fn][r] += bfv[fm * 16 + fn * 4 + r];
    // online softmax (16-lane group = one q-row)
    float fsc[2][4];
#pragma unroll
    for (int fm = 0; fm < 2; fm++) {
#pragma unroll
      for (int r = 0; r < 4; r++) {
        float pm = fmaxf(fmaxf(sc[fm][0][r], sc[fm][1][r]),
                         fmaxf(sc[fm][2][r], sc[fm][3][r]));
        pm = fmaxf(pm, __shfl_xor(pm, 1));
        pm = fmaxf(pm, __shfl_xor(pm, 2));
        pm = fmaxf(pm, __shfl_xor(pm, 4));
        pm = fmaxf(pm, __shfl_xor(pm, 8));
        float mn = fmaxf(ms[fm][r], pm);
        float f = __expf(ms[fm][r] - mn);
        float rs = 0.f;
#pragma unroll
        for (int fn = 0; fn < 4; fn++) {
          float pv = __expf(sc[fm][fn][r] - mn);
          sc[fm][fn][r] = pv;
          rs += pv;
        }
        rs += __shfl_xor(rs, 1);
        rs += __shfl_xor(rs, 2);
        rs += __shfl_xor(rs, 4);
        rs += __shfl_xor(rs, 8);
        ls[fm][r] = ls[fm][r] * f + rs;
        ms[fm][r] = mn;
        fsc[fm][r] = f;
      }
    }
#pragma unroll
    for (int fm = 0; fm < 2; fm++)
#pragma unroll
      for (int fn = 0; fn < 4; fn++)
#pragma unroll
        for (int r = 0; r < 4; r++) oa[fm][fn][r] *= fsc[fm][r];
    // write P (bf16) to per-wave swizzled LDS
#pragma unroll
    for (int fm = 0; fm < 2; fm++)
#pragma unroll
      for (int fn = 0; fn < 4; fn++)
#pragma unroll
        for (int r = 0; r < 4; r++) {
          int row = fm * 16 + ((l >> 4) << 2) + r;
          int kc = fn * 16 + (l & 15);
          int off = row * 128 + (((kc >> 3) ^ (row & 7)) << 4) + (kc & 7) * 2;
          *(u16*)((char*)Pw + off) = f2bf(sc[fm][fn][r]);
        }
    // PV
#pragma unroll
    for (int kk = 0; kk < 2; kk++) {
      bf16x8 ap[2], bv_[4];
#pragma unroll
      for (int fm = 0; fm < 2; fm++) {
        int row = fm * 16 + (l & 15);
        int slot = (kk * 4 + (l >> 4)) ^ (row & 7);
        ap[fm] = *(const bf16x8*)((const char*)Pw + row * 128 + slot * 16);
      }
#pragma unroll
      for (int fn = 0; fn < 4; fn++) {
        int row = fn * 16 + (l & 15);
        int slot = (kk * 4 + (l >> 4)) ^ (row & 7);
        bv_[fn] = *(const bf16x8*)((const char*)Vs + row * 128 + slot * 16);
      }
#pragma unroll
      for (int fm = 0; fm < 2; fm++)
#pragma unroll
        for (int fn = 0; fn < 4; fn++)
          oa[fm][fn] = __builtin_amdgcn_mfma_f32_16x16x32_bf16(
              ap[fm], bv_[fn], oa[fm][fn], 0, 0, 0);
    }
  }
  // epilogue: normalize + store ctx bf16
#pragma unroll
  for (int fm = 0; fm < 2; fm++) {
    float inv[4];
#pragma unroll
    for (int r = 0; r < 4; r++) inv[r] = 1.f / ls[fm][r];
#pragma unroll
    for (int fn = 0; fn < 4; fn++) {
      int col = h * 64 + fn * 16 + (l & 15);
#pragma unroll
      for (int r = 0; r < 4; r++) {
        int row = b * SS + q0 + w * 32 + fm * 16 + ((l >> 4) << 2) + r;
        ctx[(size_t)row * DD + col] = f2bf(oa[fm][fn][r] * inv[r]);
      }
    }
  }
}

// --------------------------------------------------------------------------
// residual + LayerNorm (fp32), writes next h (fp32) and hb (bf16)
__global__ __launch_bounds__(256) void k_ln(const float* __restrict__ x,
                                            const float* __restrict__ res,
                                            const float* __restrict__ g,
                                            const float* __restrict__ bta,
                                            float* __restrict__ ho,
                                            u16* __restrict__ hbo) {
  int row = blockIdx.x;
  int t = threadIdx.x;
  const float* xr = x + (size_t)row * DD;
  const float* rr = res + (size_t)row * DD;
  float v[3];
  float s = 0.f, s2 = 0.f;
#pragma unroll
  for (int j = 0; j < 3; j++) {
    float a = xr[t + j * 256] + rr[t + j * 256];
    v[j] = a;
    s += a;
    s2 += a * a;
  }
#pragma unroll
  for (int m = 1; m < 64; m <<= 1) {
    s += __shfl_xor(s, m);
    s2 += __shfl_xor(s2, m);
  }
  __shared__ float red[8];
  int w = t >> 6, l = t & 63;
  if (l == 0) { red[w] = s; red[4 + w] = s2; }
  __syncthreads();
  s = red[0] + red[1] + red[2] + red[3];
  s2 = red[4] + red[5] + red[6] + red[7];
  float mean = s * (1.f / 768.f);
  float var = s2 * (1.f / 768.f) - mean * mean;
  float rstd = rsqrtf(var + 1e-12f);
#pragma unroll
  for (int j = 0; j < 3; j++) {
    int c = t + j * 256;
    float y = (v[j] - mean) * rstd * g[c] + bta[c];
    ho[(size_t)row * DD + c] = y;
    hbo[(size_t)row * DD + c] = f2bf(y);
  }
}

// --------------------------------------------------------------------------
extern "C" void kernel_launch(void* const* d_in, const int* in_sizes, int n_in,
                              void* d_out, int out_size, void* d_ws,
                              size_t ws_size, hipStream_t stream) {
  const float* hid = (const float*)d_in[0];
  const unsigned char* msk = (const unsigned char*)d_in[1];
  const int* pos = (const int*)d_in[2];
  const int* bbx = (const int*)d_in[3];
  const float* qw = (const float*)d_in[4];
  const float* qbv = (const float*)d_in[5];
  const float* kw = (const float*)d_in[6];
  const float* kbv = (const float*)d_in[7];
  const float* vw = (const float*)d_in[8];
  const float* vbv = (const float*)d_in[9];
  const float* ow = (const float*)d_in[10];
  const float* obv = (const float*)d_in[11];
  const float* lng = (const float*)d_in[12];
  const float* lnb = (const float*)d_in[13];
  const float* wpb = (const float*)d_in[14];
  const float* wxb = (const float*)d_in[15];
  const float* wyb = (const float*)d_in[16];
  float* outp = (float*)d_out;

  // workspace carve (total ~244.5 MiB)
  char* p = (char*)d_ws;
  u16* bias = (u16*)p;   p += (size_t)201326592;  // [B,H,S,S] bf16, pre-blocked
  float* hbuf = (float*)p; p += 12582912;         // residual stream fp32
  u16* hb = (u16*)p;     p += 6291456;            // h in bf16
  u16* qo = (u16*)p;     p += 6291456;
  u16* ko = (u16*)p;     p += 6291456;
  u16* vo = (u16*)p;     p += 6291456;
  u16* vtb = (u16*)p;    p += 6291456;            // V transposed [BH][64][S]
  u16* ctxb = (u16*)p;   p += 6291456;
  u16* wtb = (u16*)p;    p += 4718592;            // per-layer wT bf16 (q,k,v,o)
  float* att = (float*)qo;                        // alias q+k (dead by O-GEMM)

  k_hb<<<dim3(3072), dim3(256), 0, stream>>>((const float4*)hid, (uint2*)hb,
                                             786432);
  k_bias<<<dim3(1024), dim3(256), 0, stream>>>(pos, bbx, msk, wpb, wxb, wyb,
                                               bias);
  for (int l = 0; l < NLAYER; l++) {
    k_wconv<<<dim3(2304), dim3(256), 0, stream>>>(qw, kw, vw, ow, l, wtb);
    k_gemm_qkv<<<dim3(576), dim3(256), 0, stream>>>(
        hb, wtb, qbv + l * DD, kbv + l * DD, vbv + l * DD, qo, ko, vo);
    k_vt<<<dim3(768), dim3(256), 0, stream>>>(vo, vtb);
    k_attn<<<dim3(384), dim3(256), 0, stream>>>(qo, ko, vtb, bias, ctxb);
    k_gemm_o<<<dim3(192), dim3(256), 0, stream>>>(
        ctxb, wtb + (size_t)3 * DD * DD, obv + l * DD, att);
    k_ln<<<dim3(4096), dim3(256), 0, stream>>>(
        att, l == 0 ? hid : (const float*)hbuf, lng + l * DD, lnb + l * DD,
        l == 11 ? outp : hbuf, hb);
  }
}

// Round 3
// 2020.708 us; speedup vs baseline: 1.2722x; 1.2722x over previous
//
#include <hip/hip_runtime.h>

// ---------------------------------------------------------------------------
// ErnieLayout encoder, 12 layers, B=2 S=2048 D=768 H=12 DH=64, bf16 MFMA.
// ---------------------------------------------------------------------------

#define BB 2
#define SS 2048
#define DD 768
#define HH 12
#define NLAYER 12
#define MM 4096  // BB*SS

typedef unsigned short u16;
typedef __attribute__((ext_vector_type(8))) short bf16x8;
typedef __attribute__((ext_vector_type(4))) float f32x4;

__device__ __forceinline__ u16 f2bf(float f) {
  unsigned u = __float_as_uint(f);
  unsigned r = (u + 0x7FFFu + ((u >> 16) & 1u)) >> 16;
  return (u16)r;
}
__device__ __forceinline__ float bf2f(unsigned u) {
  return __uint_as_float(u << 16);
}

__device__ __forceinline__ void g2lds16(const void* g, void* l) {
  __builtin_amdgcn_global_load_lds(
      (const __attribute__((address_space(1))) unsigned int*)g,
      (__attribute__((address_space(3))) unsigned int*)l, 16, 0, 0);
}

// --------------------------------------------------------------------------
// hidden fp32 -> bf16
__global__ __launch_bounds__(256) void k_hb(const float4* __restrict__ x,
                                            uint2* __restrict__ o, int n4) {
  int i = blockIdx.x * 256 + threadIdx.x;
  if (i < n4) {
    float4 v = x[i];
    uint2 r;
    r.x = (unsigned)f2bf(v.x) | ((unsigned)f2bf(v.y) << 16);
    r.y = (unsigned)f2bf(v.z) | ((unsigned)f2bf(v.w) << 16);
    o[i] = r;
  }
}

// --------------------------------------------------------------------------
// relative-position bucketing (mirrors reference fp32 math)
__device__ __forceinline__ int bucket1(int rel) {
  int ret = rel > 0 ? 16 : 0;
  int n = rel < 0 ? -rel : rel;
  if (n < 8) return ret + n;
  int v = 8 + (int)(logf((float)n * 0.125f) * 2.8853900817779268f); // 8/ln(16)
  return ret + (v < 15 ? v : 15);
}
__device__ __forceinline__ int bucket2(int rel) {
  int ret = rel > 0 ? 32 : 0;
  int n = rel < 0 ? -rel : rel;
  if (n < 16) return ret + n;
  int v = 16 + (int)(logf((float)n * 0.0625f) * 5.7707801635558537f); // 16/ln(16)
  return ret + (v < 31 ? v : 31);
}

// Bias precompute. Layout: [b][h][qt(32)][kt(32)][tid(256)][sub(16)] bf16,
// sub = fn*4 + r, matching k_attn's per-thread fragment order. Buckets are
// PACKED into one int each (5+6+6+1 bits) so no spill; 16 live ints/thread.
__global__ __launch_bounds__(256) void k_bias(
    const int* __restrict__ pos, const int* __restrict__ bbx,
    const unsigned char* __restrict__ msk,
    const float* __restrict__ wp, const float* __restrict__ wx,
    const float* __restrict__ wy, u16* __restrict__ bias) {
  int bid = blockIdx.x;                 // b*1024 + qt*32 + kt
  int b = bid >> 10, qt = (bid >> 5) & 31, kt = bid & 31;
  __shared__ float swp[384], swx[768], swy[768];
  __shared__ int pq[64], xq[64], yq[64], pk[64], xk[64], yk[64];
  __shared__ unsigned char mk[64];
  int t = threadIdx.x;
  for (int i = t; i < 384; i += 256) swp[i] = wp[i];
  for (int i = t; i < 768; i += 256) { swx[i] = wx[i]; swy[i] = wy[i]; }
  int q0 = qt * 64, k0 = kt * 64;
  if (t < 64) {
    int gi = b * SS + q0 + t;
    pq[t] = pos[gi]; xq[t] = bbx[gi * 4]; yq[t] = bbx[gi * 4 + 3];
  } else if (t < 128) {
    int j = t - 64, gi = b * SS + k0 + j;
    pk[j] = pos[gi]; xk[j] = bbx[gi * 4]; yk[j] = bbx[gi * 4 + 3];
    mk[j] = msk[b * SS + k0 + j];
  }
  __syncthreads();
  int w = t >> 6, l = t & 63;
  int packed[16];
#pragma unroll
  for (int fn = 0; fn < 4; fn++)
#pragma unroll
    for (int r = 0; r < 4; r++) {
      int ql = w * 16 + ((l >> 4) << 2) + r;
      int kl = fn * 16 + (l & 15);
      int b1 = bucket1(pk[kl] - pq[ql]);
      int b2 = bucket2(xk[kl] - xq[ql]);
      int b3 = bucket2(yk[kl] - yq[ql]);
      packed[fn * 4 + r] = b1 | (b2 << 5) | (b3 << 11) | (mk[kl] ? (1 << 17) : 0);
    }
  for (int h = 0; h < 12; h++) {
    const float* rp = swp + h * 32;
    const float* rx = swx + h * 64;
    const float* ry = swy + h * 64;
    unsigned pk2[8];
#pragma unroll
    for (int j = 0; j < 8; j++) {
      int p0 = packed[2 * j], p1 = packed[2 * j + 1];
      float f0 = rp[p0 & 31] + rx[(p0 >> 5) & 63] + ry[(p0 >> 11) & 63];
      float f1 = rp[p1 & 31] + rx[(p1 >> 5) & 63] + ry[(p1 >> 11) & 63];
      if (p0 >> 17) f0 = -3.0e38f;
      if (p1 >> 17) f1 = -3.0e38f;
      pk2[j] = (unsigned)f2bf(f0) | ((unsigned)f2bf(f1) << 16);
    }
    u16* dst = bias +
        ((size_t)((b * 12 + h) * 1024 + qt * 32 + kt) * 256 + t) * 16;
    ((uint4*)dst)[0] = make_uint4(pk2[0], pk2[1], pk2[2], pk2[3]);
    ((uint4*)dst)[1] = make_uint4(pk2[4], pk2[5], pk2[6], pk2[7]);
  }
}

// --------------------------------------------------------------------------
// per-layer weight convert fp32 -> bf16, transposed to [out][in]
__global__ __launch_bounds__(256) void k_wconv(
    const float* __restrict__ qw, const float* __restrict__ kw,
    const float* __restrict__ vw, const float* __restrict__ ow, int layer,
    u16* __restrict__ wt) {
  int bid = blockIdx.x;
  int g = bid / 576, rr_ = bid % 576, nt = rr_ / 24, kt = rr_ % 24;
  const float* src = g == 0 ? qw : g == 1 ? kw : g == 2 ? vw : ow;
  src += (size_t)layer * DD * DD;
  __shared__ float sm[32][33];
  int t = threadIdx.x, c = t & 31, r0 = t >> 5;
#pragma unroll
  for (int p = 0; p < 4; p++) {
    int rr = r0 + p * 8;
    sm[rr][c] = src[(size_t)(kt * 32 + rr) * DD + nt * 32 + c];
  }
  __syncthreads();
  u16* dst = wt + (size_t)g * DD * DD;
#pragma unroll
  for (int p = 0; p < 4; p++) {
    int rn = r0 + p * 8;
    dst[(size_t)(nt * 32 + rn) * DD + kt * 32 + c] = f2bf(sm[c][rn]);
  }
}

// --------------------------------------------------------------------------
// GEMM core: C[128,128] = A[128,768] x Bt[128,768]^T, bf16 MFMA, BK=64,
// XOR-swizzled LDS, global_load_lds(16B) staging with pre-swizzled source.
__device__ __forceinline__ void gemm_core(const u16* __restrict__ A,
                                          const u16* __restrict__ Bt, u16* As,
                                          u16* Bs, f32x4 acc[4][4], int tid) {
  int w = tid >> 6, l = tid & 63;
  int wm = w >> 1, wn = w & 1;
#pragma unroll
  for (int i = 0; i < 4; i++)
#pragma unroll
    for (int j = 0; j < 4; j++) acc[i][j] = f32x4{0.f, 0.f, 0.f, 0.f};
  for (int kt = 0; kt < 12; kt++) {
    __syncthreads();
    int r0 = w * 32;
#pragma unroll
    for (int j = 0; j < 4; j++) {
      int row = r0 + j * 8 + (l >> 3);
      int sl = (l & 7) ^ (row & 7);
      g2lds16(A + (size_t)row * DD + kt * 64 + sl * 8, As + (r0 + j * 8) * 64);
      g2lds16(Bt + (size_t)row * DD + kt * 64 + sl * 8, Bs + (r0 + j * 8) * 64);
    }
    __syncthreads();
#pragma unroll
    for (int kk = 0; kk < 2; kk++) {
      bf16x8 af[4], bfr[4];
#pragma unroll
      for (int fm = 0; fm < 4; fm++) {
        int row = wm * 64 + fm * 16 + (l & 15);
        int slot = (kk * 4 + (l >> 4)) ^ (row & 7);
        af[fm] = *(const bf16x8*)((const char*)As + row * 128 + slot * 16);
      }
#pragma unroll
      for (int fn = 0; fn < 4; fn++) {
        int row = wn * 64 + fn * 16 + (l & 15);
        int slot = (kk * 4 + (l >> 4)) ^ (row & 7);
        bfr[fn] = *(const bf16x8*)((const char*)Bs + row * 128 + slot * 16);
      }
#pragma unroll
      for (int fm = 0; fm < 4; fm++)
#pragma unroll
        for (int fn = 0; fn < 4; fn++)
          acc[fm][fn] = __builtin_amdgcn_mfma_f32_16x16x32_bf16(
              af[fm], bfr[fn], acc[fm][fn], 0, 0, 0);
    }
  }
}

// fused QKV GEMM (N = 3*768), q scaled by 1/sqrt(64)
__global__ __launch_bounds__(256) void k_gemm_qkv(
    const u16* __restrict__ hb, const u16* __restrict__ wt,
    const float* __restrict__ qbias, const float* __restrict__ kbias,
    const float* __restrict__ vbias, u16* __restrict__ qo, u16* __restrict__ ko,
    u16* __restrict__ vo) {
  __shared__ __align__(16) u16 As[128 * 64];
  __shared__ __align__(16) u16 Bs[128 * 64];
  int bid = blockIdx.x;
  int mblk = bid / 18, nblk = bid % 18;
  int g = nblk / 6, nb = nblk % 6;
  const u16* A = hb + (size_t)mblk * 128 * DD;
  const u16* Bt = wt + (size_t)g * DD * DD + (size_t)nb * 128 * DD;
  f32x4 acc[4][4];
  gemm_core(A, Bt, As, Bs, acc, threadIdx.x);
  const float* bias = g == 0 ? qbias : g == 1 ? kbias : vbias;
  u16* out = g == 0 ? qo : g == 1 ? ko : vo;
  float scale = g == 0 ? 0.125f : 1.0f;
  int w = threadIdx.x >> 6, l = threadIdx.x & 63;
  int wm = w >> 1, wn = w & 1;
#pragma unroll
  for (int fn = 0; fn < 4; fn++) {
    int col = nb * 128 + wn * 64 + fn * 16 + (l & 15);
    float bval = bias[col];
#pragma unroll
    for (int fm = 0; fm < 4; fm++)
#pragma unroll
      for (int r = 0; r < 4; r++) {
        int row = mblk * 128 + wm * 64 + fm * 16 + ((l >> 4) << 2) + r;
        out[(size_t)row * DD + col] = f2bf((acc[fm][fn][r] + bval) * scale);
      }
  }
}

// O-projection GEMM, fp32 output (residual+LN done in k_ln)
__global__ __launch_bounds__(256) void k_gemm_o(const u16* __restrict__ ctx,
                                                const u16* __restrict__ wto,
                                                const float* __restrict__ obias,
                                                float* __restrict__ outp) {
  __shared__ __align__(16) u16 As[128 * 64];
  __shared__ __align__(16) u16 Bs[128 * 64];
  int bid = blockIdx.x;
  int mblk = bid / 6, nblk = bid % 6;
  const u16* A = ctx + (size_t)mblk * 128 * DD;
  const u16* Bt = wto + (size_t)nblk * 128 * DD;
  f32x4 acc[4][4];
  gemm_core(A, Bt, As, Bs, acc, threadIdx.x);
  int w = threadIdx.x >> 6, l = threadIdx.x & 63;
  int wm = w >> 1, wn = w & 1;
#pragma unroll
  for (int fn = 0; fn < 4; fn++) {
    int col = nblk * 128 + wn * 64 + fn * 16 + (l & 15);
    float bval = obias[col];
#pragma unroll
    for (int fm = 0; fm < 4; fm++)
#pragma unroll
      for (int r = 0; r < 4; r++) {
        int row = mblk * 128 + wm * 64 + fm * 16 + ((l >> 4) << 2) + r;
        outp[(size_t)row * DD + col] = acc[fm][fn][r] + bval;
      }
  }
}

// --------------------------------------------------------------------------
// V transpose: [B,S,H,DH] -> [B*H][DH=64][S=2048] so attn can stage linearly
__global__ __launch_bounds__(256) void k_vt(const u16* __restrict__ vo,
                                            u16* __restrict__ vt) {
  int bid = blockIdx.x;
  int bh = bid >> 5, st = bid & 31;
  int b = bh / 12, h = bh % 12;
  int s0 = st * 64;
  __shared__ u16 sm[64][68];
  int t = threadIdx.x, c = t & 63, r0 = t >> 6;
#pragma unroll
  for (int p = 0; p < 16; p++) {
    int r = r0 + p * 4;
    sm[r][c] = vo[(size_t)(b * SS + s0 + r) * DD + h * 64 + c];
  }
  __syncthreads();
#pragma unroll
  for (int p = 0; p < 16; p++) {
    int d = r0 + p * 4;
    vt[(size_t)(bh * 64 + d) * SS + s0 + c] = sm[c][d];
  }
}

// --------------------------------------------------------------------------
// Flash attention v2: block = (bh, qtile of 64), 4 waves x 16 q-rows.
// Q + bias fragments direct from global (k-contiguous); K/V double-buffered
// LDS with 2-phase prefetch (stage next BEFORE compute, 1 barrier/tile).
__global__ __launch_bounds__(256) void k_attn(
    const u16* __restrict__ q, const u16* __restrict__ kmat,
    const u16* __restrict__ vt, const u16* __restrict__ bias,
    u16* __restrict__ ctx) {
  int bid = blockIdx.x;          // bh*32 + qt
  int qt = bid & 31, bh = bid >> 5;
  int b = bh / 12, h = bh % 12;
  __shared__ __align__(16) u16 Ks[2][64 * 64];
  __shared__ __align__(16) u16 Vs[2][64 * 64];
  __shared__ __align__(16) u16 Ps[4][16 * 64];
  int tid = threadIdx.x, w = tid >> 6, l = tid & 63;
  int q0 = qt * 64;
  // Q fragments (A operand) directly from global: row = l&15, k-contig 8.
  const u16* qp = q + (size_t)(b * SS + q0 + w * 16 + (l & 15)) * DD + h * 64 +
                  (l >> 4) * 8;
  bf16x8 aq0 = *(const bf16x8*)qp;
  bf16x8 aq1 = *(const bf16x8*)(qp + 32);
  const u16* kb_ = kmat + (size_t)(b * SS) * DD + h * 64;
  const u16* vb_ = vt + (size_t)bh * 64 * SS;
  const u16* bb_ = bias + ((size_t)(bh * 32 + qt) * 32 * 256 + tid) * 16;
  f32x4 oa[4];
  float ms[4], ls[4];
#pragma unroll
  for (int fn = 0; fn < 4; fn++) oa[fn] = f32x4{0.f, 0.f, 0.f, 0.f};
#pragma unroll
  for (int r = 0; r < 4; r++) { ms[r] = -3.0e38f; ls[r] = 0.f; }
  int srow = tid >> 3, sc8 = tid & 7;

  auto STAGE = [&](int kt, int buf) {
#pragma unroll
    for (int j = 0; j < 2; j++) {
      int rr = srow + j * 32;
      int sl = sc8 ^ (rr & 7);
      g2lds16(kb_ + (size_t)(kt * 64 + rr) * DD + sl * 8,
              &Ks[buf][tid * 8 + j * 2048]);
      g2lds16(vb_ + (size_t)rr * SS + kt * 64 + sl * 8,
              &Vs[buf][tid * 8 + j * 2048]);
    }
  };

  STAGE(0, 0);
  __syncthreads();
  for (int kt = 0; kt < 32; kt++) {
    int buf = kt & 1;
    if (kt < 31) STAGE(kt + 1, buf ^ 1);
    // bias fragments (pre-blocked, coalesced 32B/thread)
    const uint4* bp = (const uint4*)(bb_ + (size_t)kt * 4096);
    uint4 u0 = bp[0], u1 = bp[1];
    // QK^T
    f32x4 sc[4];
#pragma unroll
    for (int fn = 0; fn < 4; fn++) sc[fn] = f32x4{0.f, 0.f, 0.f, 0.f};
#pragma unroll
    for (int kk = 0; kk < 2; kk++) {
      bf16x8 bk[4];
#pragma unroll
      for (int fn = 0; fn < 4; fn++) {
        int row = fn * 16 + (l & 15);
        int slot = (kk * 4 + (l >> 4)) ^ (row & 7);
        bk[fn] = *(const bf16x8*)((const char*)&Ks[buf][0] + row * 128 +
                                  slot * 16);
      }
#pragma unroll
      for (int fn = 0; fn < 4; fn++)
        sc[fn] = __builtin_amdgcn_mfma_f32_16x16x32_bf16(
            kk == 0 ? aq0 : aq1, bk[fn], sc[fn], 0, 0, 0);
    }
    // bias add: sub = fn*4 + r, pairs packed lo/hi
    unsigned ua[8] = {u0.x, u0.y, u0.z, u0.w, u1.x, u1.y, u1.z, u1.w};
#pragma unroll
    for (int fn = 0; fn < 4; fn++)
#pragma unroll
      for (int r = 0; r < 4; r++) {
        int i = fn * 4 + r;
        unsigned uv = ua[i >> 1];
        sc[fn][r] += bf2f((i & 1) ? (uv >> 16) : (uv & 0xffffu));
      }
    // online softmax: row = (l>>4)*4 + r, reduce across 16 lanes (cols)
    float fscal[4];
#pragma unroll
    for (int r = 0; r < 4; r++) {
      float pm = fmaxf(fmaxf(sc[0][r], sc[1][r]), fmaxf(sc[2][r], sc[3][r]));
      pm = fmaxf(pm, __shfl_xor(pm, 1));
      pm = fmaxf(pm, __shfl_xor(pm, 2));
      pm = fmaxf(pm, __shfl_xor(pm, 4));
      pm = fmaxf(pm, __shfl_xor(pm, 8));
      float mn = fmaxf(ms[r], pm);
      float f = __expf(ms[r] - mn);
      float rs = 0.f;
#pragma unroll
      for (int fn = 0; fn < 4; fn++) {
        float pv = __expf(sc[fn][r] - mn);
        sc[fn][r] = pv;
        rs += pv;
      }
      rs += __shfl_xor(rs, 1);
      rs += __shfl_xor(rs, 2);
      rs += __shfl_xor(rs, 4);
      rs += __shfl_xor(rs, 8);
      ls[r] = ls[r] * f + rs;
      ms[r] = mn;
      fscal[r] = f;
    }
#pragma unroll
    for (int fn = 0; fn < 4; fn++)
#pragma unroll
      for (int r = 0; r < 4; r++) oa[fn][r] *= fscal[r];
    // P -> per-wave swizzled LDS (bf16)
#pragma unroll
    for (int fn = 0; fn < 4; fn++)
#pragma unroll
      for (int r = 0; r < 4; r++) {
        int prow = ((l >> 4) << 2) + r;
        int pcol = fn * 16 + (l & 15);
        int off = prow * 128 + (((pcol >> 3) ^ (prow & 7)) << 4) +
                  (pcol & 7) * 2;
        *(u16*)((char*)&Ps[w][0] + off) = f2bf(sc[fn][r]);
      }
    // PV
#pragma unroll
    for (int kk = 0; kk < 2; kk++) {
      int prow = l & 15;
      int slot = (kk * 4 + (l >> 4)) ^ (prow & 7);
      bf16x8 ap = *(const bf16x8*)((const char*)&Ps[w][0] + prow * 128 +
                                   slot * 16);
      bf16x8 bv[4];
#pragma unroll
      for (int fn = 0; fn < 4; fn++) {
        int row = fn * 16 + (l & 15);
        int sl2 = (kk * 4 + (l >> 4)) ^ (row & 7);
        bv[fn] = *(const bf16x8*)((const char*)&Vs[buf][0] + row * 128 +
                                  sl2 * 16);
      }
#pragma unroll
      for (int fn = 0; fn < 4; fn++)
        oa[fn] = __builtin_amdgcn_mfma_f32_16x16x32_bf16(ap, bv[fn], oa[fn],
                                                         0, 0, 0);
    }
    __syncthreads();
  }
  // epilogue: normalize + store ctx bf16
  float inv[4];
#pragma unroll
  for (int r = 0; r < 4; r++) inv[r] = 1.f / ls[r];
#pragma unroll
  for (int fn = 0; fn < 4; fn++) {
    int col = h * 64 + fn * 16 + (l & 15);
#pragma unroll
    for (int r = 0; r < 4; r++) {
      int row = b * SS + q0 + w * 16 + ((l >> 4) << 2) + r;
      ctx[(size_t)row * DD + col] = f2bf(oa[fn][r] * inv[r]);
    }
  }
}

// --------------------------------------------------------------------------
// residual + LayerNorm (fp32), writes next h (fp32) and hb (bf16)
__global__ __launch_bounds__(256) void k_ln(const float* __restrict__ x,
                                            const float* __restrict__ res,
                                            const float* __restrict__ g,
                                            const float* __restrict__ bta,
                                            float* __restrict__ ho,
                                            u16* __restrict__ hbo) {
  int row = blockIdx.x;
  int t = threadIdx.x;
  const float* xr = x + (size_t)row * DD;
  const float* rr = res + (size_t)row * DD;
  float v[3];
  float s = 0.f, s2 = 0.f;
#pragma unroll
  for (int j = 0; j < 3; j++) {
    float a = xr[t + j * 256] + rr[t + j * 256];
    v[j] = a;
    s += a;
    s2 += a * a;
  }
#pragma unroll
  for (int m = 1; m < 64; m <<= 1) {
    s += __shfl_xor(s, m);
    s2 += __shfl_xor(s2, m);
  }
  __shared__ float red[8];
  int w = t >> 6, l = t & 63;
  if (l == 0) { red[w] = s; red[4 + w] = s2; }
  __syncthreads();
  s = red[0] + red[1] + red[2] + red[3];
  s2 = red[4] + red[5] + red[6] + red[7];
  float mean = s * (1.f / 768.f);
  float var = s2 * (1.f / 768.f) - mean * mean;
  float rstd = rsqrtf(var + 1e-12f);
#pragma unroll
  for (int j = 0; j < 3; j++) {
    int c = t + j * 256;
    float y = (v[j] - mean) * rstd * g[c] + bta[c];
    ho[(size_t)row * DD + c] = y;
    hbo[(size_t)row * DD + c] = f2bf(y);
  }
}

// --------------------------------------------------------------------------
extern "C" void kernel_launch(void* const* d_in, const int* in_sizes, int n_in,
                              void* d_out, int out_size, void* d_ws,
                              size_t ws_size, hipStream_t stream) {
  const float* hid = (const float*)d_in[0];
  const unsigned char* msk = (const unsigned char*)d_in[1];
  const int* pos = (const int*)d_in[2];
  const int* bbx = (const int*)d_in[3];
  const float* qw = (const float*)d_in[4];
  const float* qbv = (const float*)d_in[5];
  const float* kw = (const float*)d_in[6];
  const float* kbv = (const float*)d_in[7];
  const float* vw = (const float*)d_in[8];
  const float* vbv = (const float*)d_in[9];
  const float* ow = (const float*)d_in[10];
  const float* obv = (const float*)d_in[11];
  const float* lng = (const float*)d_in[12];
  const float* lnb = (const float*)d_in[13];
  const float* wpb = (const float*)d_in[14];
  const float* wxb = (const float*)d_in[15];
  const float* wyb = (const float*)d_in[16];
  float* outp = (float*)d_out;

  // workspace carve (total ~244.5 MiB)
  char* p = (char*)d_ws;
  u16* bias = (u16*)p;   p += (size_t)201326592;  // [B,H,S,S] bf16, pre-blocked
  float* hbuf = (float*)p; p += 12582912;         // residual stream fp32
  u16* hb = (u16*)p;     p += 6291456;            // h in bf16
  u16* qo = (u16*)p;     p += 6291456;
  u16* ko = (u16*)p;     p += 6291456;
  u16* vo = (u16*)p;     p += 6291456;
  u16* vtb = (u16*)p;    p += 6291456;            // V transposed [BH][64][S]
  u16* ctxb = (u16*)p;   p += 6291456;
  u16* wtb = (u16*)p;    p += 4718592;            // per-layer wT bf16 (q,k,v,o)
  float* att = (float*)qo;                        // alias q+k (dead by O-GEMM)

  k_hb<<<dim3(3072), dim3(256), 0, stream>>>((const float4*)hid, (uint2*)hb,
                                             786432);
  k_bias<<<dim3(2048), dim3(256), 0, stream>>>(pos, bbx, msk, wpb, wxb, wyb,
                                               bias);
  for (int l = 0; l < NLAYER; l++) {
    k_wconv<<<dim3(2304), dim3(256), 0, stream>>>(qw, kw, vw, ow, l, wtb);
    k_gemm_qkv<<<dim3(576), dim3(256), 0, stream>>>(
        hb, wtb, qbv + l * DD, kbv + l * DD, vbv + l * DD, qo, ko, vo);
    k_vt<<<dim3(768), dim3(256), 0, stream>>>(vo, vtb);
    k_attn<<<dim3(768), dim3(256), 0, stream>>>(qo, ko, vtb, bias, ctxb);
    k_gemm_o<<<dim3(192), dim3(256), 0, stream>>>(
        ctxb, wtb + (size_t)3 * DD * DD, obv + l * DD, att);
    k_ln<<<dim3(4096), dim3(256), 0, stream>>>(
        att, l == 0 ? hid : (const float*)hbuf, lng + l * DD, lnb + l * DD,
        l == 11 ? outp : hbuf, hb);
  }
}

// Round 4
// 1622.484 us; speedup vs baseline: 1.5844x; 1.2454x over previous
//
#include <hip/hip_runtime.h>

// ---------------------------------------------------------------------------
// ErnieLayout encoder, 12 layers, B=2 S=2048 D=768 H=12 DH=64, bf16 MFMA.
// Attention uses swapped-operand MFMA (S^T = K·Q^T, O^T = V^T·P^T) so each
// lane owns one q-row: per-lane online softmax, 4 shfl/tile, packed P path.
// ---------------------------------------------------------------------------

#define BB 2
#define SS 2048
#define DD 768
#define HH 12
#define NLAYER 12
#define MM 4096  // BB*SS

typedef unsigned short u16;
typedef __attribute__((ext_vector_type(8))) short bf16x8;
typedef __attribute__((ext_vector_type(4))) float f32x4;

#define LOG2E 1.44269504088896340736f

__device__ __forceinline__ u16 f2bf(float f) {
  unsigned u = __float_as_uint(f);
  unsigned r = (u + 0x7FFFu + ((u >> 16) & 1u)) >> 16;
  return (u16)r;
}
__device__ __forceinline__ float bf2f(unsigned u) {
  return __uint_as_float(u << 16);
}
__device__ __forceinline__ unsigned cvtpk(float a, float b) {
  unsigned r;
  asm("v_cvt_pk_bf16_f32 %0, %1, %2" : "=v"(r) : "v"(a), "v"(b));
  return r;
}
__device__ __forceinline__ float exp2v(float x) {
  float r;
  asm("v_exp_f32 %0, %1" : "=v"(r) : "v"(x));
  return r;
}

__device__ __forceinline__ void g2lds16(const void* g, void* l) {
  __builtin_amdgcn_global_load_lds(
      (const __attribute__((address_space(1))) unsigned int*)g,
      (__attribute__((address_space(3))) unsigned int*)l, 16, 0, 0);
}

// --------------------------------------------------------------------------
// hidden fp32 -> bf16
__global__ __launch_bounds__(256) void k_hb(const float4* __restrict__ x,
                                            uint2* __restrict__ o, int n4) {
  int i = blockIdx.x * 256 + threadIdx.x;
  if (i < n4) {
    float4 v = x[i];
    uint2 r;
    r.x = (unsigned)f2bf(v.x) | ((unsigned)f2bf(v.y) << 16);
    r.y = (unsigned)f2bf(v.z) | ((unsigned)f2bf(v.w) << 16);
    o[i] = r;
  }
}

// --------------------------------------------------------------------------
// relative-position bucketing (mirrors reference fp32 math)
__device__ __forceinline__ int bucket1(int rel) {
  int ret = rel > 0 ? 16 : 0;
  int n = rel < 0 ? -rel : rel;
  if (n < 8) return ret + n;
  int v = 8 + (int)(logf((float)n * 0.125f) * 2.8853900817779268f); // 8/ln(16)
  return ret + (v < 15 ? v : 15);
}
__device__ __forceinline__ int bucket2(int rel) {
  int ret = rel > 0 ? 32 : 0;
  int n = rel < 0 ? -rel : rel;
  if (n < 16) return ret + n;
  int v = 16 + (int)(logf((float)n * 0.0625f) * 5.7707801635558537f); // 16/ln(16)
  return ret + (v < 31 ? v : 31);
}

// Bias precompute. Layout: [b][h][qt(32)][kt(32)][tid(256)][sub(16)] bf16,
// sub = fn*4 + r with the SWAPPED attn mapping: thread's q-row = w*16+(l&15),
// kv = fn*16 + (l>>4)*4 + r. Values pre-scaled by log2(e); mask -> -3e38.
__global__ __launch_bounds__(256) void k_bias(
    const int* __restrict__ pos, const int* __restrict__ bbx,
    const unsigned char* __restrict__ msk,
    const float* __restrict__ wp, const float* __restrict__ wx,
    const float* __restrict__ wy, u16* __restrict__ bias) {
  int bid = blockIdx.x;                 // b*1024 + qt*32 + kt
  int b = bid >> 10, qt = (bid >> 5) & 31, kt = bid & 31;
  __shared__ float swp[384], swx[768], swy[768];
  __shared__ int pq[64], xq[64], yq[64], pk[64], xk[64], yk[64];
  __shared__ unsigned char mk[64];
  int t = threadIdx.x;
  for (int i = t; i < 384; i += 256) swp[i] = wp[i];
  for (int i = t; i < 768; i += 256) { swx[i] = wx[i]; swy[i] = wy[i]; }
  int q0 = qt * 64, k0 = kt * 64;
  if (t < 64) {
    int gi = b * SS + q0 + t;
    pq[t] = pos[gi]; xq[t] = bbx[gi * 4]; yq[t] = bbx[gi * 4 + 3];
  } else if (t < 128) {
    int j = t - 64, gi = b * SS + k0 + j;
    pk[j] = pos[gi]; xk[j] = bbx[gi * 4]; yk[j] = bbx[gi * 4 + 3];
    mk[j] = msk[b * SS + k0 + j];
  }
  __syncthreads();
  int w = t >> 6, l = t & 63;
  int hi = l >> 4;
  int qlr = w * 16 + (l & 15);
  int pql = pq[qlr], xql = xq[qlr], yql = yq[qlr];
  int packed[16];
#pragma unroll
  for (int fn = 0; fn < 4; fn++)
#pragma unroll
    for (int r = 0; r < 4; r++) {
      int kl = fn * 16 + hi * 4 + r;
      int b1 = bucket1(pk[kl] - pql);
      int b2 = bucket2(xk[kl] - xql);
      int b3 = bucket2(yk[kl] - yql);
      packed[fn * 4 + r] = b1 | (b2 << 5) | (b3 << 11) | (mk[kl] ? (1 << 17) : 0);
    }
  for (int h = 0; h < 12; h++) {
    const float* rp = swp + h * 32;
    const float* rx = swx + h * 64;
    const float* ry = swy + h * 64;
    unsigned pk2[8];
#pragma unroll
    for (int j = 0; j < 8; j++) {
      int p0 = packed[2 * j], p1 = packed[2 * j + 1];
      float f0 = (rp[p0 & 31] + rx[(p0 >> 5) & 63] + ry[(p0 >> 11) & 63]) * LOG2E;
      float f1 = (rp[p1 & 31] + rx[(p1 >> 5) & 63] + ry[(p1 >> 11) & 63]) * LOG2E;
      if (p0 >> 17) f0 = -3.0e38f;
      if (p1 >> 17) f1 = -3.0e38f;
      pk2[j] = (unsigned)f2bf(f0) | ((unsigned)f2bf(f1) << 16);
    }
    u16* dst = bias +
        ((size_t)((b * 12 + h) * 1024 + qt * 32 + kt) * 256 + t) * 16;
    ((uint4*)dst)[0] = make_uint4(pk2[0], pk2[1], pk2[2], pk2[3]);
    ((uint4*)dst)[1] = make_uint4(pk2[4], pk2[5], pk2[6], pk2[7]);
  }
}

// --------------------------------------------------------------------------
// per-layer weight convert fp32 -> bf16, transposed to [out][in]
__global__ __launch_bounds__(256) void k_wconv(
    const float* __restrict__ qw, const float* __restrict__ kw,
    const float* __restrict__ vw, const float* __restrict__ ow, int layer,
    u16* __restrict__ wt) {
  int bid = blockIdx.x;
  int g = bid / 576, rr_ = bid % 576, nt = rr_ / 24, kt = rr_ % 24;
  const float* src = g == 0 ? qw : g == 1 ? kw : g == 2 ? vw : ow;
  src += (size_t)layer * DD * DD;
  __shared__ float sm[32][33];
  int t = threadIdx.x, c = t & 31, r0 = t >> 5;
#pragma unroll
  for (int p = 0; p < 4; p++) {
    int rr = r0 + p * 8;
    sm[rr][c] = src[(size_t)(kt * 32 + rr) * DD + nt * 32 + c];
  }
  __syncthreads();
  u16* dst = wt + (size_t)g * DD * DD;
#pragma unroll
  for (int p = 0; p < 4; p++) {
    int rn = r0 + p * 8;
    dst[(size_t)(nt * 32 + rn) * DD + kt * 32 + c] = f2bf(sm[c][rn]);
  }
}

// --------------------------------------------------------------------------
// GEMM core: C[128,128] = A[128,768] x Bt[128,768]^T, bf16 MFMA, BK=64,
// XOR-swizzled LDS, global_load_lds(16B) staging with pre-swizzled source.
__device__ __forceinline__ void gemm_core(const u16* __restrict__ A,
                                          const u16* __restrict__ Bt, u16* As,
                                          u16* Bs, f32x4 acc[4][4], int tid) {
  int w = tid >> 6, l = tid & 63;
  int wm = w >> 1, wn = w & 1;
#pragma unroll
  for (int i = 0; i < 4; i++)
#pragma unroll
    for (int j = 0; j < 4; j++) acc[i][j] = f32x4{0.f, 0.f, 0.f, 0.f};
  for (int kt = 0; kt < 12; kt++) {
    __syncthreads();
    int r0 = w * 32;
#pragma unroll
    for (int j = 0; j < 4; j++) {
      int row = r0 + j * 8 + (l >> 3);
      int sl = (l & 7) ^ (row & 7);
      g2lds16(A + (size_t)row * DD + kt * 64 + sl * 8, As + (r0 + j * 8) * 64);
      g2lds16(Bt + (size_t)row * DD + kt * 64 + sl * 8, Bs + (r0 + j * 8) * 64);
    }
    __syncthreads();
#pragma unroll
    for (int kk = 0; kk < 2; kk++) {
      bf16x8 af[4], bfr[4];
#pragma unroll
      for (int fm = 0; fm < 4; fm++) {
        int row = wm * 64 + fm * 16 + (l & 15);
        int slot = (kk * 4 + (l >> 4)) ^ (row & 7);
        af[fm] = *(const bf16x8*)((const char*)As + row * 128 + slot * 16);
      }
#pragma unroll
      for (int fn = 0; fn < 4; fn++) {
        int row = wn * 64 + fn * 16 + (l & 15);
        int slot = (kk * 4 + (l >> 4)) ^ (row & 7);
        bfr[fn] = *(const bf16x8*)((const char*)Bs + row * 128 + slot * 16);
      }
#pragma unroll
      for (int fm = 0; fm < 4; fm++)
#pragma unroll
        for (int fn = 0; fn < 4; fn++)
          acc[fm][fn] = __builtin_amdgcn_mfma_f32_16x16x32_bf16(
              af[fm], bfr[fn], acc[fm][fn], 0, 0, 0);
    }
  }
}

// fused QKV GEMM (N = 3*768), q scaled by log2(e)/sqrt(64)
__global__ __launch_bounds__(256) void k_gemm_qkv(
    const u16* __restrict__ hb, const u16* __restrict__ wt,
    const float* __restrict__ qbias, const float* __restrict__ kbias,
    const float* __restrict__ vbias, u16* __restrict__ qo, u16* __restrict__ ko,
    u16* __restrict__ vo) {
  __shared__ __align__(16) u16 As[128 * 64];
  __shared__ __align__(16) u16 Bs[128 * 64];
  int bid = blockIdx.x;
  int mblk = bid / 18, nblk = bid % 18;
  int g = nblk / 6, nb = nblk % 6;
  const u16* A = hb + (size_t)mblk * 128 * DD;
  const u16* Bt = wt + (size_t)g * DD * DD + (size_t)nb * 128 * DD;
  f32x4 acc[4][4];
  gemm_core(A, Bt, As, Bs, acc, threadIdx.x);
  const float* bias = g == 0 ? qbias : g == 1 ? kbias : vbias;
  u16* out = g == 0 ? qo : g == 1 ? ko : vo;
  float scale = g == 0 ? 0.125f * LOG2E : 1.0f;
  int w = threadIdx.x >> 6, l = threadIdx.x & 63;
  int wm = w >> 1, wn = w & 1;
#pragma unroll
  for (int fn = 0; fn < 4; fn++) {
    int col = nb * 128 + wn * 64 + fn * 16 + (l & 15);
    float bval = bias[col];
#pragma unroll
    for (int fm = 0; fm < 4; fm++)
#pragma unroll
      for (int r = 0; r < 4; r++) {
        int row = mblk * 128 + wm * 64 + fm * 16 + ((l >> 4) << 2) + r;
        out[(size_t)row * DD + col] = f2bf((acc[fm][fn][r] + bval) * scale);
      }
  }
}

// O-projection GEMM, fp32 output (residual+LN done in k_ln)
__global__ __launch_bounds__(256) void k_gemm_o(const u16* __restrict__ ctx,
                                                const u16* __restrict__ wto,
                                                const float* __restrict__ obias,
                                                float* __restrict__ outp) {
  __shared__ __align__(16) u16 As[128 * 64];
  __shared__ __align__(16) u16 Bs[128 * 64];
  int bid = blockIdx.x;
  int mblk = bid / 6, nblk = bid % 6;
  const u16* A = ctx + (size_t)mblk * 128 * DD;
  const u16* Bt = wto + (size_t)nblk * 128 * DD;
  f32x4 acc[4][4];
  gemm_core(A, Bt, As, Bs, acc, threadIdx.x);
  int w = threadIdx.x >> 6, l = threadIdx.x & 63;
  int wm = w >> 1, wn = w & 1;
#pragma unroll
  for (int fn = 0; fn < 4; fn++) {
    int col = nblk * 128 + wn * 64 + fn * 16 + (l & 15);
    float bval = obias[col];
#pragma unroll
    for (int fm = 0; fm < 4; fm++)
#pragma unroll
      for (int r = 0; r < 4; r++) {
        int row = mblk * 128 + wm * 64 + fm * 16 + ((l >> 4) << 2) + r;
        outp[(size_t)row * DD + col] = acc[fm][fn][r] + bval;
      }
  }
}

// --------------------------------------------------------------------------
// V transpose: [B,S,H,DH] -> [B*H][DH=64][S=2048] so attn can stage linearly
__global__ __launch_bounds__(256) void k_vt(const u16* __restrict__ vo,
                                            u16* __restrict__ vt) {
  int bid = blockIdx.x;
  int bh = bid >> 5, st = bid & 31;
  int b = bh / 12, h = bh % 12;
  int s0 = st * 64;
  __shared__ u16 sm[64][68];
  int t = threadIdx.x, c = t & 63, r0 = t >> 6;
#pragma unroll
  for (int p = 0; p < 16; p++) {
    int r = r0 + p * 4;
    sm[r][c] = vo[(size_t)(b * SS + s0 + r) * DD + h * 64 + c];
  }
  __syncthreads();
#pragma unroll
  for (int p = 0; p < 16; p++) {
    int d = r0 + p * 4;
    vt[(size_t)(bh * 64 + d) * SS + s0 + c] = sm[c][d];
  }
}

// --------------------------------------------------------------------------
// Flash attention v3 (swapped operands): block = (bh, qtile of 64),
// 4 waves x 16 q-rows; lane owns q-row = w*16+(l&15). S^T = mfma(K,Q),
// O^T = mfma(V^T, P^T). Per-lane online softmax (2+2 shfl), packed P path.
__global__ __launch_bounds__(256) void k_attn(
    const u16* __restrict__ qm, const u16* __restrict__ kmat,
    const u16* __restrict__ vt, const u16* __restrict__ bias,
    u16* __restrict__ ctx) {
  int bid = blockIdx.x;          // bh*32 + qt
  int qt = bid & 31, bh = bid >> 5;
  int b = bh / 12, h = bh % 12;
  __shared__ __align__(16) u16 Ks[2][64 * 64];
  __shared__ __align__(16) u16 Vs[2][64 * 64];
  __shared__ __align__(16) u16 Ps[4][16 * 64];
  int tid = threadIdx.x, w = tid >> 6, l = tid & 63;
  int hi = l >> 4, qr = l & 15;
  int q0 = qt * 64;
  // Q fragment (B operand): row q = w*16+qr, d-contig 8 at hi*8 (+32 for kk=1)
  const u16* qp = qm + (size_t)(b * SS + q0 + w * 16 + qr) * DD + h * 64 +
                  hi * 8;
  bf16x8 aq0 = *(const bf16x8*)qp;
  bf16x8 aq1 = *(const bf16x8*)(qp + 32);
  const u16* kb_ = kmat + (size_t)(b * SS) * DD + h * 64;
  const u16* vb_ = vt + (size_t)bh * 64 * SS;
  const u16* bb_ = bias + ((size_t)(bh * 32 + qt) * 32 * 256 + tid) * 16;
  f32x4 oa[4];
#pragma unroll
  for (int fn = 0; fn < 4; fn++) oa[fn] = f32x4{0.f, 0.f, 0.f, 0.f};
  float m_ = -3.0e38f, l_ = 0.f;
  int srow = tid >> 3, sc8 = tid & 7;

  auto STAGE = [&](int kt, int buf) {
#pragma unroll
    for (int j = 0; j < 2; j++) {
      int rr = srow + j * 32;
      int sl = sc8 ^ (rr & 7);
      g2lds16(kb_ + (size_t)(kt * 64 + rr) * DD + sl * 8,
              &Ks[buf][tid * 8 + j * 2048]);
      g2lds16(vb_ + (size_t)rr * SS + kt * 64 + sl * 8,
              &Vs[buf][tid * 8 + j * 2048]);
    }
  };

  STAGE(0, 0);
  uint4 bu0 = ((const uint4*)bb_)[0];
  uint4 bu1 = ((const uint4*)bb_)[1];
  uint4 nb0 = bu0, nb1 = bu1;
  char* pw = (char*)&Ps[w][0] + qr * 128;
  int qs = (qr & 7) << 4;
  __syncthreads();

  for (int kt = 0; kt < 32; kt++) {
    int buf = kt & 1;
    if (kt < 31) STAGE(kt + 1, buf ^ 1);
    // QK^T swapped: sc[fn] = S^T tile, lane holds kv = fn*16+hi*4+r, q = qr
    f32x4 sc[4];
#pragma unroll
    for (int fn = 0; fn < 4; fn++) sc[fn] = f32x4{0.f, 0.f, 0.f, 0.f};
#pragma unroll
    for (int kk = 0; kk < 2; kk++) {
      bf16x8 aq = kk == 0 ? aq0 : aq1;
#pragma unroll
      for (int fn = 0; fn < 4; fn++) {
        int row = fn * 16 + qr;
        int slot = (kk * 4 + hi) ^ (row & 7);
        bf16x8 bk = *(const bf16x8*)((const char*)&Ks[buf][0] + row * 128 +
                                     slot * 16);
        sc[fn] = __builtin_amdgcn_mfma_f32_16x16x32_bf16(bk, aq, sc[fn],
                                                         0, 0, 0);
      }
    }
    // bias add (sub = fn*4+r), then prefetch next tile's bias
    unsigned ua[8] = {bu0.x, bu0.y, bu0.z, bu0.w, bu1.x, bu1.y, bu1.z, bu1.w};
#pragma unroll
    for (int fn = 0; fn < 4; fn++)
#pragma unroll
      for (int r = 0; r < 4; r++) {
        int i = fn * 4 + r;
        unsigned uv = ua[i >> 1];
        sc[fn][r] += bf2f((i & 1) ? (uv >> 16) : (uv & 0xffffu));
      }
    if (kt < 31) {
      const uint4* bpn = (const uint4*)(bb_ + (size_t)(kt + 1) * 4096);
      nb0 = bpn[0];
      nb1 = bpn[1];
    }
    // per-lane online softmax (base-2); row max over 16 regs + 2 shfl
    float pm = fmaxf(fmaxf(fmaxf(sc[0][0], sc[0][1]), fmaxf(sc[0][2], sc[0][3])),
                     fmaxf(fmaxf(sc[1][0], sc[1][1]), fmaxf(sc[1][2], sc[1][3])));
    pm = fmaxf(pm,
         fmaxf(fmaxf(fmaxf(sc[2][0], sc[2][1]), fmaxf(sc[2][2], sc[2][3])),
               fmaxf(fmaxf(sc[3][0], sc[3][1]), fmaxf(sc[3][2], sc[3][3]))));
    pm = fmaxf(pm, __shfl_xor(pm, 16));
    pm = fmaxf(pm, __shfl_xor(pm, 32));
    if (__any(pm > m_)) {
      float mn = fmaxf(m_, pm);
      float f = exp2v(m_ - mn);
#pragma unroll
      for (int fn = 0; fn < 4; fn++)
#pragma unroll
        for (int r = 0; r < 4; r++) oa[fn][r] *= f;
      l_ *= f;
      m_ = mn;
    }
    float rs = 0.f;
#pragma unroll
    for (int fn = 0; fn < 4; fn++)
#pragma unroll
      for (int r = 0; r < 4; r++) {
        float pv = exp2v(sc[fn][r] - m_);
        sc[fn][r] = pv;
        rs += pv;
      }
    rs += __shfl_xor(rs, 16);
    rs += __shfl_xor(rs, 32);
    l_ += rs;
    // pack P row-segment (kv-contig per lane) and write 4x ds_write_b64
#pragma unroll
    for (int fn = 0; fn < 4; fn++) {
      unsigned w0 = cvtpk(sc[fn][0], sc[fn][1]);
      unsigned w1 = cvtpk(sc[fn][2], sc[fn][3]);
      *(uint2*)(pw + ((fn * 32 + hi * 8) ^ qs)) = make_uint2(w0, w1);
    }
    // PV: O^T += V^T-frag x P^T-frag
#pragma unroll
    for (int ck = 0; ck < 2; ck++) {
      bf16x8 pt = *(const bf16x8*)(pw + ((ck * 64 + hi * 16) ^ qs));
#pragma unroll
      for (int fn = 0; fn < 4; fn++) {
        int row = fn * 16 + qr;
        int slot = (ck * 4 + hi) ^ (row & 7);
        bf16x8 av = *(const bf16x8*)((const char*)&Vs[buf][0] + row * 128 +
                                     slot * 16);
        oa[fn] = __builtin_amdgcn_mfma_f32_16x16x32_bf16(av, pt, oa[fn],
                                                         0, 0, 0);
      }
    }
    bu0 = nb0;
    bu1 = nb1;
    __syncthreads();
  }
  // epilogue: normalize + packed 8B stores (d = fn*16 + hi*4 + 0..3)
  float inv = 1.0f / l_;
  u16* cp = ctx + (size_t)(b * SS + q0 + w * 16 + qr) * DD + h * 64 + hi * 4;
#pragma unroll
  for (int fn = 0; fn < 4; fn++) {
    unsigned w0 = cvtpk(oa[fn][0] * inv, oa[fn][1] * inv);
    unsigned w1 = cvtpk(oa[fn][2] * inv, oa[fn][3] * inv);
    *(uint2*)(cp + fn * 16) = make_uint2(w0, w1);
  }
}

// --------------------------------------------------------------------------
// residual + LayerNorm (fp32), writes next h (fp32) and hb (bf16)
__global__ __launch_bounds__(256) void k_ln(const float* __restrict__ x,
                                            const float* __restrict__ res,
                                            const float* __restrict__ g,
                                            const float* __restrict__ bta,
                                            float* __restrict__ ho,
                                            u16* __restrict__ hbo) {
  int row = blockIdx.x;
  int t = threadIdx.x;
  const float* xr = x + (size_t)row * DD;
  const float* rr = res + (size_t)row * DD;
  float v[3];
  float s = 0.f, s2 = 0.f;
#pragma unroll
  for (int j = 0; j < 3; j++) {
    float a = xr[t + j * 256] + rr[t + j * 256];
    v[j] = a;
    s += a;
    s2 += a * a;
  }
#pragma unroll
  for (int m = 1; m < 64; m <<= 1) {
    s += __shfl_xor(s, m);
    s2 += __shfl_xor(s2, m);
  }
  __shared__ float red[8];
  int w = t >> 6, l = t & 63;
  if (l == 0) { red[w] = s; red[4 + w] = s2; }
  __syncthreads();
  s = red[0] + red[1] + red[2] + red[3];
  s2 = red[4] + red[5] + red[6] + red[7];
  float mean = s * (1.f / 768.f);
  float var = s2 * (1.f / 768.f) - mean * mean;
  float rstd = rsqrtf(var + 1e-12f);
#pragma unroll
  for (int j = 0; j < 3; j++) {
    int c = t + j * 256;
    float y = (v[j] - mean) * rstd * g[c] + bta[c];
    ho[(size_t)row * DD + c] = y;
    hbo[(size_t)row * DD + c] = f2bf(y);
  }
}

// --------------------------------------------------------------------------
extern "C" void kernel_launch(void* const* d_in, const int* in_sizes, int n_in,
                              void* d_out, int out_size, void* d_ws,
                              size_t ws_size, hipStream_t stream) {
  const float* hid = (const float*)d_in[0];
  const unsigned char* msk = (const unsigned char*)d_in[1];
  const int* pos = (const int*)d_in[2];
  const int* bbx = (const int*)d_in[3];
  const float* qw = (const float*)d_in[4];
  const float* qbv = (const float*)d_in[5];
  const float* kw = (const float*)d_in[6];
  const float* kbv = (const float*)d_in[7];
  const float* vw = (const float*)d_in[8];
  const float* vbv = (const float*)d_in[9];
  const float* ow = (const float*)d_in[10];
  const float* obv = (const float*)d_in[11];
  const float* lng = (const float*)d_in[12];
  const float* lnb = (const float*)d_in[13];
  const float* wpb = (const float*)d_in[14];
  const float* wxb = (const float*)d_in[15];
  const float* wyb = (const float*)d_in[16];
  float* outp = (float*)d_out;

  // workspace carve (total ~244.5 MiB)
  char* p = (char*)d_ws;
  u16* bias = (u16*)p;   p += (size_t)201326592;  // [B,H,S,S] bf16, pre-blocked
  float* hbuf = (float*)p; p += 12582912;         // residual stream fp32
  u16* hb = (u16*)p;     p += 6291456;            // h in bf16
  u16* qo = (u16*)p;     p += 6291456;
  u16* ko = (u16*)p;     p += 6291456;
  u16* vo = (u16*)p;     p += 6291456;
  u16* vtb = (u16*)p;    p += 6291456;            // V transposed [BH][64][S]
  u16* ctxb = (u16*)p;   p += 6291456;
  u16* wtb = (u16*)p;    p += 4718592;            // per-layer wT bf16 (q,k,v,o)
  float* att = (float*)qo;                        // alias q+k (dead by O-GEMM)

  k_hb<<<dim3(3072), dim3(256), 0, stream>>>((const float4*)hid, (uint2*)hb,
                                             786432);
  k_bias<<<dim3(2048), dim3(256), 0, stream>>>(pos, bbx, msk, wpb, wxb, wyb,
                                               bias);
  for (int l = 0; l < NLAYER; l++) {
    k_wconv<<<dim3(2304), dim3(256), 0, stream>>>(qw, kw, vw, ow, l, wtb);
    k_gemm_qkv<<<dim3(576), dim3(256), 0, stream>>>(
        hb, wtb, qbv + l * DD, kbv + l * DD, vbv + l * DD, qo, ko, vo);
    k_vt<<<dim3(768), dim3(256), 0, stream>>>(vo, vtb);
    k_attn<<<dim3(768), dim3(256), 0, stream>>>(qo, ko, vtb, bias, ctxb);
    k_gemm_o<<<dim3(192), dim3(256), 0, stream>>>(
        ctxb, wtb + (size_t)3 * DD * DD, obv + l * DD, att);
    k_ln<<<dim3(4096), dim3(256), 0, stream>>>(
        att, l == 0 ? hid : (const float*)hbuf, lng + l * DD, lnb + l * DD,
        l == 11 ? outp : hbuf, hb);
  }
}